// Round 1
// baseline (1073.421 us; speedup 1.0000x reference)
//
#include <hip/hip_runtime.h>

// Problem constants (match reference setup_inputs)
#define Bz 16
#define Tz 256
#define T2z 16
#define Hz 256
#define DRz 64
#define DEPTHz 8
#define ROWSz (Bz * (Tz + 2))   // 4128 rows in flat h/c tables
#define NODESz (Bz * Tz)        // 4096 tree nodes

__device__ __forceinline__ float sigmoid_(float x) { return 1.0f / (1.0f + __expf(-x)); }
__device__ __forceinline__ float tanh_(float x) {
    float e = __expf(2.0f * x);
    return 1.0f - 2.0f / (e + 1.0f);
}

// C[M,N] = A[M,K] @ W[K,N] (+ bias). Requires K % 16 == 0, N % 64 == 0.
// 64x64 tile, 256 threads, 4x4 micro-tile per thread, K-tiles of 16.
__global__ __launch_bounds__(256) void gemm_k(const float* __restrict__ A,
                                              const float* __restrict__ W,
                                              const float* __restrict__ bias,
                                              float* __restrict__ C,
                                              int M, int N, int K) {
    __shared__ float As[16][64];
    __shared__ float Bs[16][64];
    const int tid = threadIdx.x;
    const int tx = tid & 15, ty = tid >> 4;
    const int bx = blockIdx.x, by = blockIdx.y;
    const int n0 = bx * 64 + tx * 4;
    const int m0 = by * 64 + ty * 4;
    float acc[4][4] = {};
    for (int kt = 0; kt < K; kt += 16) {
        const int e = tid * 4;
        // A tile: 64(m) x 16(k); each thread loads float4 along k
        const int am = e >> 4;       // 0..63
        const int ak = e & 15;       // 0,4,8,12
        const int gm = by * 64 + am;
        float4 av = make_float4(0.f, 0.f, 0.f, 0.f);
        if (gm < M) av = *(const float4*)(A + (size_t)gm * K + kt + ak);
        As[ak + 0][am] = av.x; As[ak + 1][am] = av.y;
        As[ak + 2][am] = av.z; As[ak + 3][am] = av.w;
        // B tile: 16(k) x 64(n); float4 along n (coalesced)
        const int bk = e >> 6;       // 0..15
        const int bn = e & 63;       // multiple of 4
        float4 bv = *(const float4*)(W + (size_t)(kt + bk) * N + bx * 64 + bn);
        Bs[bk][bn + 0] = bv.x; Bs[bk][bn + 1] = bv.y;
        Bs[bk][bn + 2] = bv.z; Bs[bk][bn + 3] = bv.w;
        __syncthreads();
#pragma unroll
        for (int kk = 0; kk < 16; kk++) {
            float a[4], b[4];
#pragma unroll
            for (int i = 0; i < 4; i++) a[i] = As[kk][ty * 4 + i];
#pragma unroll
            for (int j = 0; j < 4; j++) b[j] = Bs[kk][tx * 4 + j];
#pragma unroll
            for (int i = 0; i < 4; i++)
#pragma unroll
                for (int j = 0; j < 4; j++)
                    acc[i][j] = fmaf(a[i], b[j], acc[i][j]);
        }
        __syncthreads();
    }
#pragma unroll
    for (int i = 0; i < 4; i++) {
        const int m = m0 + i;
        if (m < M) {
            float4 v = make_float4(acc[i][0], acc[i][1], acc[i][2], acc[i][3]);
            if (bias) {
                v.x += bias[n0 + 0]; v.y += bias[n0 + 1];
                v.z += bias[n0 + 2]; v.w += bias[n0 + 3];
            }
            *(float4*)(C + (size_t)m * N + n0) = v;
        }
    }
}

// Per-row L2 renorm (F.embedding max_norm=2 semantics) of the h and c tables.
// One block per row (4128 blocks), 256 threads = one per h element.
__global__ __launch_bounds__(256) void renorm_k(const float* __restrict__ h,
                                                const float* __restrict__ c,
                                                float* __restrict__ rnh,
                                                float* __restrict__ rnc) {
    __shared__ float sm[8];
    const int r = blockIdx.x, tid = threadIdx.x;
    const size_t base = (size_t)r * Hz + tid;
    const float hv = h[base], cv = c[base];
    float a = hv * hv, b = cv * cv;
#pragma unroll
    for (int off = 32; off > 0; off >>= 1) {
        a += __shfl_down(a, off);
        b += __shfl_down(b, off);
    }
    if ((tid & 63) == 0) { sm[tid >> 6] = a; sm[4 + (tid >> 6)] = b; }
    __syncthreads();
    const float nh = sqrtf(sm[0] + sm[1] + sm[2] + sm[3]);
    const float nc = sqrtf(sm[4] + sm[5] + sm[6] + sm[7]);
    const float sh = nh > 2.0f ? 2.0f / nh : 1.0f;
    const float sc = nc > 2.0f ? 2.0f / nc : 1.0f;
    rnh[base] = hv * sh;
    rnc[base] = cv * sc;
}

// Fused attention + child aggregation. One block per node (b,t), 256 threads.
// Computes: logits (tanh(proj_h_gathered + deprel_proj) . attnv), masked
// softmax over 16 children, h_j = sum ch*mask*a, fsum = sum sigmoid(xf+hf)*cc*mask.
__global__ __launch_bounds__(256) void attn_k(const int* __restrict__ trees,
                                              const float* __restrict__ cmask,
                                              const float* __restrict__ rnh,
                                              const float* __restrict__ rnc,
                                              const float* __restrict__ projh,
                                              const float* __restrict__ projf,
                                              const float* __restrict__ dp,   // may be null
                                              const float* __restrict__ cdep,
                                              const float* __restrict__ Wdep,
                                              const float* __restrict__ attnv,
                                              const float* __restrict__ xiouf,
                                              float* __restrict__ hj,
                                              float* __restrict__ fsum) {
    __shared__ int sidx[16];
    __shared__ float smask[16];
    __shared__ float slog[16];
    const int node = blockIdx.x;
    const int tid = threadIdx.x;
    if (tid < 16) {
        sidx[tid] = trees[node * 16 + tid];
        smask[tid] = cmask[node * 16 + tid];
    }
    __syncthreads();
    const int wave = tid >> 6, lane = tid & 63;
    const float av0 = attnv[lane], av1 = attnv[lane + 64];
    const float av2 = attnv[lane + 128], av3 = attnv[lane + 192];
    // wave w computes logits for children j = 4w..4w+3
    for (int jj = 0; jj < 4; jj++) {
        const int j = wave * 4 + jj;
        const float m = smask[j];
        float lg = -1e30f;  // masked: exp -> exactly 0 (<= 1e-45 rel in ref; below fp32 eps)
        if (m != 0.0f) {
            const int idx = sidx[j];
            const float* ph = projh + (size_t)idx * Hz;
            float d0, d1, d2, d3;
            if (dp) {
                const float* dpp = dp + ((size_t)node * 16 + j) * Hz;
                d0 = dpp[lane]; d1 = dpp[lane + 64];
                d2 = dpp[lane + 128]; d3 = dpp[lane + 192];
            } else {
                // ws too small for the precomputed deprel projection: recompute
                d0 = d1 = d2 = d3 = 0.0f;
                const float* cd = cdep + ((size_t)node * 16 + j) * DRz;
                for (int k = 0; k < DRz; k++) {
                    const float cv = cd[k];  // uniform across lanes (broadcast)
                    const float* wr = Wdep + (size_t)k * Hz;
                    d0 = fmaf(cv, wr[lane], d0);
                    d1 = fmaf(cv, wr[lane + 64], d1);
                    d2 = fmaf(cv, wr[lane + 128], d2);
                    d3 = fmaf(cv, wr[lane + 192], d3);
                }
            }
            float p = tanh_(ph[lane] + d0) * av0
                    + tanh_(ph[lane + 64] + d1) * av1
                    + tanh_(ph[lane + 128] + d2) * av2
                    + tanh_(ph[lane + 192] + d3) * av3;
#pragma unroll
            for (int off = 32; off > 0; off >>= 1) p += __shfl_down(p, off);
            lg = p;
        }
        if (lane == 0) slog[j] = lg;
    }
    __syncthreads();
    // softmax over 16 (each thread redundantly; trivial cost)
    float mx = slog[0];
#pragma unroll
    for (int j = 1; j < 16; j++) mx = fmaxf(mx, slog[j]);
    float den = 0.0f;
#pragma unroll
    for (int j = 0; j < 16; j++) den += __expf(slog[j] - mx);
    const float inv = 1.0f / den;
    // accumulate over children; thread tid handles h-dim element tid (coalesced gathers)
    const int b = node >> 8;  // T = 256
    float hjv = 0.0f, fsv = 0.0f;
    for (int j = 0; j < 16; j++) {
        const float m = smask[j];
        if (m == 0.0f) continue;  // exact: contributions are multiplied by mask in ref
        const int idx = sidx[j];
        const float aj = __expf(slog[j] - mx) * inv;
        const float chv = rnh[(size_t)idx * Hz + tid];
        const float ccv = rnc[(size_t)idx * Hz + tid];
        const float pf = projf[(size_t)idx * Hz + tid];
        // faithful to reference bug: x_f indexed by child slot j, not node t
        const float xf = xiouf[((size_t)(b * Tz + j)) * (4 * Hz) + 3 * Hz + tid];
        hjv = fmaf(chv, aj, hjv);
        fsv = fmaf(sigmoid_(xf + pf), ccv, fsv);
    }
    hj[(size_t)node * Hz + tid] = hjv;
    fsum[(size_t)node * Hz + tid] = fsv;
}

// LSTM gates + state update. Writes into the pad-shifted h/c tables
// (row b*(T+2) + t + 2) for levels 0..6, or h_new -> d_out at the last level.
__global__ __launch_bounds__(256) void gate_k(const float* __restrict__ xiouf,
                                              const float* __restrict__ hiou,
                                              const float* __restrict__ fsum,
                                              float* __restrict__ hout,
                                              float* __restrict__ cout,
                                              int last) {
    const int node = blockIdx.x, tid = threadIdx.x;
    const float* x = xiouf + (size_t)node * (4 * Hz);
    const float* hio = hiou + (size_t)node * (3 * Hz);
    const float ig = sigmoid_(x[tid] + hio[tid]);
    const float og = sigmoid_(x[Hz + tid] + hio[Hz + tid]);
    const float ug = tanh_(x[2 * Hz + tid] + hio[2 * Hz + tid]);
    const float cn = fmaf(ig, ug, fsum[(size_t)node * Hz + tid]);
    const float hn = og * tanh_(cn);
    if (last) {
        hout[(size_t)node * Hz + tid] = hn;
    } else {
        const int b = node >> 8, t = node & 255;
        const size_t r = ((size_t)b * (Tz + 2) + t + 2) * Hz + tid;
        hout[r] = hn;
        cout[r] = cn;
    }
}

extern "C" void kernel_launch(void* const* d_in, const int* in_sizes, int n_in,
                              void* d_out, int out_size, void* d_ws, size_t ws_size,
                              hipStream_t stream) {
    const float* tok     = (const float*)d_in[0];
    const int*   trees   = (const int*)d_in[1];
    const float* cmask   = (const float*)d_in[2];
    // d_in[3] = max_depth scalar (constant 8, hardcoded)
    const float* cdep    = (const float*)d_in[4];
    const float* W_xiouf = (const float*)d_in[5];
    const float* b_xiouf = (const float*)d_in[6];
    const float* W_hiou  = (const float*)d_in[7];
    const float* b_hiou  = (const float*)d_in[8];
    const float* W_hf    = (const float*)d_in[9];
    const float* b_hf    = (const float*)d_in[10];
    const float* W_dep   = (const float*)d_in[11];
    const float* W_hproj = (const float*)d_in[12];
    const float* W_attnv = (const float*)d_in[13];
    float* out = (float*)d_out;

    // Workspace layout (fp32)
    float* p = (float*)d_ws;
    float* h_buf  = p; p += (size_t)ROWSz * Hz;          // 4128 x 256
    float* c_buf  = p; p += (size_t)ROWSz * Hz;          // contiguous with h_buf
    float* rn_h   = p; p += (size_t)ROWSz * Hz;
    float* rn_c   = p; p += (size_t)ROWSz * Hz;
    float* projh  = p; p += (size_t)ROWSz * Hz;
    float* projf  = p; p += (size_t)ROWSz * Hz;
    float* h_j    = p; p += (size_t)NODESz * Hz;
    float* fsumb  = p; p += (size_t)NODESz * Hz;
    float* h_iou  = p; p += (size_t)NODESz * 3 * Hz;
    float* x_iouf = p; p += (size_t)NODESz * 4 * Hz;
    float* dpb    = p; p += (size_t)NODESz * T2z * Hz;   // 64 MB, optional
    const size_t need_bytes = (size_t)((const char*)p - (const char*)d_ws);
    const int have_dp = (ws_size >= need_bytes) ? 1 : 0;

    // h/c tables start at zero (ws is poisoned each call)
    hipMemsetAsync(h_buf, 0, (size_t)2 * ROWSz * Hz * sizeof(float), stream);

    // Hoisted loop-invariant GEMMs
    gemm_k<<<dim3((4 * Hz) / 64, (NODESz + 63) / 64), 256, 0, stream>>>(
        tok, W_xiouf, b_xiouf, x_iouf, NODESz, 4 * Hz, 256);
    if (have_dp)
        gemm_k<<<dim3(Hz / 64, (NODESz * T2z + 63) / 64), 256, 0, stream>>>(
            cdep, W_dep, nullptr, dpb, NODESz * T2z, Hz, DRz);

    for (int lvl = 0; lvl < DEPTHz; lvl++) {
        renorm_k<<<ROWSz, 256, 0, stream>>>(h_buf, c_buf, rn_h, rn_c);
        // Project the 4128-row table once; gathers pick up projected rows (16x FLOP save)
        gemm_k<<<dim3(Hz / 64, (ROWSz + 63) / 64), 256, 0, stream>>>(
            rn_h, W_hproj, nullptr, projh, ROWSz, Hz, Hz);
        gemm_k<<<dim3(Hz / 64, (ROWSz + 63) / 64), 256, 0, stream>>>(
            rn_h, W_hf, b_hf, projf, ROWSz, Hz, Hz);
        attn_k<<<NODESz, 256, 0, stream>>>(trees, cmask, rn_h, rn_c, projh, projf,
                                           have_dp ? dpb : (const float*)nullptr,
                                           cdep, W_dep, W_attnv, x_iouf, h_j, fsumb);
        gemm_k<<<dim3((3 * Hz) / 64, (NODESz + 63) / 64), 256, 0, stream>>>(
            h_j, W_hiou, b_hiou, h_iou, NODESz, 3 * Hz, Hz);
        const int last = (lvl == DEPTHz - 1);
        gate_k<<<NODESz, 256, 0, stream>>>(x_iouf, h_iou, fsumb,
                                           last ? out : h_buf, c_buf, last);
    }
}

// Round 2
// 577.047 us; speedup vs baseline: 1.8602x; 1.8602x over previous
//
#include <hip/hip_runtime.h>
#include <hip/hip_bf16.h>

#define Bz 16
#define Tz 256
#define T2z 16
#define Hz 256
#define DRz 64
#define DEPTHz 8
#define ROWSz (Bz * (Tz + 2))   // 4128 rows in flat h/c tables
#define ROWSP 4160              // padded to multiple of 64 for GEMM tiles
#define NODESz (Bz * Tz)        // 4096 tree nodes

typedef short bf16x8 __attribute__((ext_vector_type(8)));
typedef float f32x4 __attribute__((ext_vector_type(4)));

__device__ __forceinline__ float sigmoid_(float x) { return 1.0f / (1.0f + __expf(-x)); }
__device__ __forceinline__ float tanh_(float x) {
    float e = __expf(2.0f * x);
    return 1.0f - 2.0f / (e + 1.0f);
}
__device__ __forceinline__ short f2b(float f) {
    __hip_bfloat16 h = __float2bfloat16(f);
    return *(short*)&h;
}
// async global->LDS, 16B per lane; LDS dest = wave-uniform base + lane*16
__device__ __forceinline__ void gload16(const short* g, short* l) {
    __builtin_amdgcn_global_load_lds((const __attribute__((address_space(1))) void*)g,
                                     (__attribute__((address_space(3))) void*)l, 16, 0, 0);
}

// C[M,N] = A[M,K]_bf16 @ BT[N,K]_bf16^T (+ bias). M = gridDim.y*64 (padded),
// N = gridDim.x*64, K % 32 == 0. 256 thr = 4 waves; wave w computes 64x16
// (4 m-frags x 1 n-frag) via mfma_f32_16x16x32_bf16. m97-style staging.
__global__ __launch_bounds__(256) void bgemm_k(const short* __restrict__ A,
                                               const short* __restrict__ BT,
                                               const float* __restrict__ bias,
                                               float* __restrict__ C,
                                               int K, int N) {
    __shared__ short As[64 * 32];
    __shared__ short Bs[64 * 32];
    const int tid = threadIdx.x;
    const int w = tid >> 6, lane = tid & 63;
    const int m0 = blockIdx.y * 64, n0 = blockIdx.x * 64;
    const int r16 = lane & 15, q = lane >> 4;
    f32x4 acc[4] = {};
    // wave w stages rows w*16..w*16+15 of each tile; lane l -> row w*16+(l>>2), 16B chunk (l&3)
    const short* ga = A + (size_t)(m0 + w * 16 + (lane >> 2)) * K + (lane & 3) * 8;
    const short* gb = BT + (size_t)(n0 + w * 16 + (lane >> 2)) * K + (lane & 3) * 8;
    short* la = As + w * 512;
    short* lb = Bs + w * 512;
    for (int kt = 0; kt < K; kt += 32) {
        __syncthreads();
        gload16(ga + kt, la);
        gload16(gb + kt, lb);
        __syncthreads();
        bf16x8 bfrag = *(const bf16x8*)&Bs[(w * 16 + r16) * 32 + q * 8];
#pragma unroll
        for (int i = 0; i < 4; i++) {
            bf16x8 afrag = *(const bf16x8*)&As[(i * 16 + r16) * 32 + q * 8];
            acc[i] = __builtin_amdgcn_mfma_f32_16x16x32_bf16(afrag, bfrag, acc[i], 0, 0, 0);
        }
    }
    const int col = n0 + w * 16 + r16;
    const float bv = bias ? bias[col] : 0.0f;
#pragma unroll
    for (int i = 0; i < 4; i++)
#pragma unroll
        for (int r = 0; r < 4; r++)
            C[(size_t)(m0 + i * 16 + q * 4 + r) * N + col] = acc[i][r] + bv;
}

// One-time weight prep: bf16 transposes (BT[n][k] = W[k][n]) + composed bias.
__global__ __launch_bounds__(256) void prep_w_k(const float* __restrict__ Wx,
                                                const float* __restrict__ Whp,
                                                const float* __restrict__ Whf,
                                                const float* __restrict__ bhf,
                                                const float* __restrict__ Whiou,
                                                const float* __restrict__ Wdep,
                                                short* __restrict__ WTx,
                                                short* __restrict__ WTcat,
                                                short* __restrict__ WThiou,
                                                short* __restrict__ WTdep,
                                                float* __restrict__ bias_cat) {
    int e = blockIdx.x * 256 + threadIdx.x;
    if (e < 262144) {  // W_xiouf [256,1024] -> [1024,256]
        int n = e >> 8, k = e & 255;
        WTx[e] = f2b(Wx[k * 1024 + n]);
        return;
    }
    e -= 262144;
    if (e < 131072) {  // [W_hproj | W_hf] [256,512] -> [512,256]
        int n = e >> 8, k = e & 255;
        float v = (n < 256) ? Whp[k * 256 + n] : Whf[k * 256 + (n - 256)];
        WTcat[e] = f2b(v);
        return;
    }
    e -= 131072;
    if (e < 196608) {  // W_hiou [256,768] -> [768,256]
        int n = e >> 8, k = e & 255;
        WThiou[e] = f2b(Whiou[k * 768 + n]);
        return;
    }
    e -= 196608;
    if (e < 16384) {  // W_deprel [64,256] -> [256,64]
        int n = e >> 6, k = e & 63;
        WTdep[e] = f2b(Wdep[k * 256 + n]);
        return;
    }
    e -= 16384;
    if (e < 512) bias_cat[e] = (e < 256) ? 0.0f : bhf[e - 256];
}

// fp32 -> bf16 cast, float4-vectorized. n4 = elems/4.
__global__ __launch_bounds__(256) void cast_k(const float* __restrict__ s,
                                              short* __restrict__ d, int n4) {
    int i = blockIdx.x * 256 + threadIdx.x;
    if (i < n4) {
        float4 v = ((const float4*)s)[i];
        short4 o;
        o.x = f2b(v.x); o.y = f2b(v.y); o.z = f2b(v.z); o.w = f2b(v.w);
        ((short4*)d)[i] = o;
    }
}

// Fused attention + child aggregation. One block per node, 256 threads.
__global__ __launch_bounds__(256) void attn_k(const int* __restrict__ trees,
                                              const float* __restrict__ cmask,
                                              const float* __restrict__ rn_h,
                                              const float* __restrict__ rn_c,
                                              const float* __restrict__ projcat,
                                              const float* __restrict__ dp,
                                              const float* __restrict__ attnv,
                                              const float* __restrict__ xiouf,
                                              short* __restrict__ hjb,
                                              float* __restrict__ fsum) {
    __shared__ int sidx[16];
    __shared__ float smask[16];
    __shared__ float slog[16];
    const int node = blockIdx.x, tid = threadIdx.x;
    if (tid < 16) {
        sidx[tid] = trees[node * 16 + tid];
        smask[tid] = cmask[node * 16 + tid];
    }
    __syncthreads();
    const int w = tid >> 6, lane = tid & 63;
    const float av0 = attnv[lane], av1 = attnv[lane + 64];
    const float av2 = attnv[lane + 128], av3 = attnv[lane + 192];
    for (int jj = 0; jj < 4; jj++) {  // wave w: children 4w..4w+3
        const int j = w * 4 + jj;
        float lg = -1e30f;  // masked: exp -> exactly 0 (below fp32 eps of ref's 1e-45 path)
        if (smask[j] != 0.0f) {
            const int idx = sidx[j];
            const float* ph = projcat + (size_t)idx * 512;
            const float* dpp = dp + ((size_t)node * 16 + j) * 256;
            float p = tanh_(ph[lane] + dpp[lane]) * av0
                    + tanh_(ph[lane + 64] + dpp[lane + 64]) * av1
                    + tanh_(ph[lane + 128] + dpp[lane + 128]) * av2
                    + tanh_(ph[lane + 192] + dpp[lane + 192]) * av3;
#pragma unroll
            for (int off = 32; off > 0; off >>= 1) p += __shfl_down(p, off);
            lg = p;
        }
        if (lane == 0) slog[j] = lg;
    }
    __syncthreads();
    float mx = slog[0];
#pragma unroll
    for (int j = 1; j < 16; j++) mx = fmaxf(mx, slog[j]);
    float den = 0.0f;
#pragma unroll
    for (int j = 0; j < 16; j++) den += __expf(slog[j] - mx);
    const float inv = 1.0f / den;
    const int b = node >> 8;
    float hjv = 0.0f, fsv = 0.0f;
    for (int j = 0; j < 16; j++) {
        const float m = smask[j];
        if (m == 0.0f) continue;  // exact: ref multiplies these terms by mask
        const int idx = sidx[j];
        const float aj = __expf(slog[j] - mx) * inv;
        const float chv = rn_h[(size_t)idx * 256 + tid];
        const float ccv = rn_c[(size_t)idx * 256 + tid];
        const float pf = projcat[(size_t)idx * 512 + 256 + tid];
        // faithful to reference bug: x_f indexed by child slot j, not node t
        const float xf = xiouf[((size_t)(b * Tz + j)) * 1024 + 768 + tid];
        hjv = fmaf(chv, aj, hjv);
        fsv = fmaf(sigmoid_(xf + pf), ccv, fsv);
    }
    hjb[(size_t)node * 256 + tid] = f2b(hjv);
    fsum[(size_t)node * 256 + tid] = fsv;
}

// Gates + state update + FUSED renorm of the new h/c rows (block holds full row).
__global__ __launch_bounds__(256) void gate_k(const float* __restrict__ xiouf,
                                              const float* __restrict__ hiou,
                                              const float* __restrict__ fsum,
                                              float* __restrict__ out,
                                              float* __restrict__ rn_h,
                                              float* __restrict__ rn_c,
                                              short* __restrict__ rnh_b,
                                              int last) {
    __shared__ float sm[8];
    const int node = blockIdx.x, tid = threadIdx.x;
    const float* x = xiouf + (size_t)node * 1024;
    const float* hio = hiou + (size_t)node * 768;
    const float ig = sigmoid_(x[tid] + hio[tid]);
    const float og = sigmoid_(x[256 + tid] + hio[256 + tid]);
    const float ug = tanh_(x[512 + tid] + hio[512 + tid]);
    const float cn = fmaf(ig, ug, fsum[(size_t)node * 256 + tid]);
    const float hn = og * tanh_(cn);
    if (last) {
        out[(size_t)node * 256 + tid] = hn;
        return;
    }
    float a = hn * hn, b = cn * cn;
#pragma unroll
    for (int off = 32; off > 0; off >>= 1) {
        a += __shfl_down(a, off);
        b += __shfl_down(b, off);
    }
    if ((tid & 63) == 0) { sm[tid >> 6] = a; sm[4 + (tid >> 6)] = b; }
    __syncthreads();
    const float nh = sqrtf(sm[0] + sm[1] + sm[2] + sm[3]);
    const float nc = sqrtf(sm[4] + sm[5] + sm[6] + sm[7]);
    const float sh = nh > 2.0f ? 2.0f / nh : 1.0f;
    const float sc = nc > 2.0f ? 2.0f / nc : 1.0f;
    const int bb = node >> 8, t = node & 255;
    const size_t r = ((size_t)bb * (Tz + 2) + t + 2) * 256 + tid;
    const float hr = hn * sh;
    rn_h[r] = hr;
    rn_c[r] = cn * sc;
    rnh_b[r] = f2b(hr);
}

extern "C" void kernel_launch(void* const* d_in, const int* in_sizes, int n_in,
                              void* d_out, int out_size, void* d_ws, size_t ws_size,
                              hipStream_t stream) {
    const float* tok     = (const float*)d_in[0];
    const int*   trees   = (const int*)d_in[1];
    const float* cmask   = (const float*)d_in[2];
    const float* cdep    = (const float*)d_in[4];
    const float* W_xiouf = (const float*)d_in[5];
    const float* b_xiouf = (const float*)d_in[6];
    const float* W_hiou  = (const float*)d_in[7];
    const float* b_hiou  = (const float*)d_in[8];
    const float* W_hproj = (const float*)d_in[9 - 0 + 3];  // placeholder, fixed below
    (void)W_hproj;
    const float* W_hf    = (const float*)d_in[9];
    const float* b_hf    = (const float*)d_in[10];
    const float* W_dep   = (const float*)d_in[11];
    const float* W_hp    = (const float*)d_in[12];
    const float* W_attnv = (const float*)d_in[13];
    float* out = (float*)d_out;

    // Workspace layout (bytes; rn_h/rn_c/rnh_b contiguous for one memset)
    char* p = (char*)d_ws;
    float* rn_h   = (float*)p; p += (size_t)ROWSP * Hz * 4;        // 4.26 MB
    float* rn_c   = (float*)p; p += (size_t)ROWSP * Hz * 4;        // 4.26 MB
    short* rnh_b  = (short*)p; p += (size_t)ROWSP * Hz * 2;        // 2.13 MB
    float* projcat= (float*)p; p += (size_t)ROWSP * 512 * 4;       // 8.5 MB
    short* hjb    = (short*)p; p += (size_t)NODESz * Hz * 2;       // 2 MB
    float* fsumb  = (float*)p; p += (size_t)NODESz * Hz * 4;       // 4.2 MB
    float* h_iou  = (float*)p; p += (size_t)NODESz * 768 * 4;      // 12.6 MB
    float* x_iouf = (float*)p; p += (size_t)NODESz * 1024 * 4;     // 16.8 MB
    float* dpb    = (float*)p; p += (size_t)NODESz * T2z * Hz * 4; // 67 MB
    short* tok_b  = (short*)p; p += (size_t)NODESz * Hz * 2;       // 2 MB
    short* cdep_b = (short*)p; p += (size_t)NODESz * T2z * DRz * 2;// 8.4 MB
    short* WTx    = (short*)p; p += 262144 * 2;
    short* WTcat  = (short*)p; p += 131072 * 2;
    short* WThiou = (short*)p; p += 196608 * 2;
    short* WTdep  = (short*)p; p += 16384 * 2;
    float* biascat= (float*)p; p += 512 * 4;

    // One-time (per call) weight prep + input casts
    prep_w_k<<<2370, 256, 0, stream>>>(W_xiouf, W_hp, W_hf, b_hf, W_hiou, W_dep,
                                       WTx, WTcat, WThiou, WTdep, biascat);
    cast_k<<<1024, 256, 0, stream>>>(tok, tok_b, 262144);      // 4096*256/4
    cast_k<<<4096, 256, 0, stream>>>(cdep, cdep_b, 1048576);   // 65536*64/4
    // zero rn_h | rn_c | rnh_b (pad rows + level-0 state)
    hipMemsetAsync(rn_h, 0, (size_t)ROWSP * Hz * (4 + 4 + 2), stream);

    // Hoisted loop-invariant GEMMs (bf16 MFMA)
    bgemm_k<<<dim3(16, 64), 256, 0, stream>>>(tok_b, WTx, b_xiouf, x_iouf, 256, 1024);
    bgemm_k<<<dim3(4, 1024), 256, 0, stream>>>(cdep_b, WTdep, nullptr, dpb, 64, 256);

    for (int lvl = 0; lvl < DEPTHz; lvl++) {
        // [projh | projf] over the 4160-row (padded) renormed h table
        bgemm_k<<<dim3(8, ROWSP / 64), 256, 0, stream>>>(rnh_b, WTcat, biascat,
                                                         projcat, 256, 512);
        attn_k<<<NODESz, 256, 0, stream>>>(trees, cmask, rn_h, rn_c, projcat, dpb,
                                           W_attnv, x_iouf, hjb, fsumb);
        bgemm_k<<<dim3(12, 64), 256, 0, stream>>>(hjb, WThiou, b_hiou, h_iou, 256, 768);
        const int last = (lvl == DEPTHz - 1);
        gate_k<<<NODESz, 256, 0, stream>>>(x_iouf, h_iou, fsumb, out,
                                           rn_h, rn_c, rnh_b, last);
    }
}